// Round 1
// baseline (5081.607 us; speedup 1.0000x reference)
//
#include <hip/hip_runtime.h>

#define HD 64  // hidden dim (columns of every GEMM here)

// ---------------------------------------------------------------------------
// GEMM: Y[n x 64] = X[n x K] @ W[K x 64]   (EPI==1: Y = relu(Y + bias))
// Block = 256 threads (4 waves). Each block does 64 rows; wave w owns rows
// [w*16, w*16+16), each lane owns one output column. W column slice cached in
// registers per 16-k chunk (16x reuse across rows); X reads are wave-uniform
// LDS broadcasts (conflict-free).
// ---------------------------------------------------------------------------
template <int K, int EPI>
__global__ __launch_bounds__(256) void gemm_k(const float* __restrict__ X,
                                              const float* __restrict__ W,
                                              const float* __restrict__ bias,
                                              float* __restrict__ Y, int n) {
    __shared__ float Ws[K][HD];     // W as-is: Ws[k][c] ; lanes->consecutive c = conflict-free
    __shared__ float Xs[64][K];     // 64-row X tile; reads are wave-uniform broadcasts

    const int tid  = threadIdx.x;
    const int lane = tid & 63;
    const int wid  = tid >> 6;      // 0..3
    const int row0 = blockIdx.x * 64;

    // stage W (coalesced b32)
    for (int i = tid; i < K * HD; i += 256) {
        Ws[i >> 6][i & 63] = W[i];
    }
    // stage X tile (float4, coalesced)
    {
        const int rowf4 = K / 4;
        const int nf4   = 64 * rowf4;
        const float4* Xg = (const float4*)X;
        float4* Xl = (float4*)&Xs[0][0];
        for (int i = tid; i < nf4; i += 256) {
            const int r   = i / rowf4;
            const int row = row0 + r;
            float4 v = make_float4(0.f, 0.f, 0.f, 0.f);
            if (row < n) v = Xg[(size_t)row * rowf4 + (i - r * rowf4)];
            Xl[i] = v;
        }
    }
    __syncthreads();

    float acc[16];
#pragma unroll
    for (int r = 0; r < 16; ++r) acc[r] = 0.f;

    const int rbase = wid * 16;
#pragma unroll
    for (int k0 = 0; k0 < K; k0 += 16) {
        float wreg[16];
#pragma unroll
        for (int j = 0; j < 16; ++j) wreg[j] = Ws[k0 + j][lane];
#pragma unroll
        for (int r = 0; r < 16; ++r) {
            const float4 x0 = *(const float4*)&Xs[rbase + r][k0 + 0];
            const float4 x1 = *(const float4*)&Xs[rbase + r][k0 + 4];
            const float4 x2 = *(const float4*)&Xs[rbase + r][k0 + 8];
            const float4 x3 = *(const float4*)&Xs[rbase + r][k0 + 12];
            float a = acc[r];
            a += wreg[0] * x0.x;  a += wreg[1] * x0.y;
            a += wreg[2] * x0.z;  a += wreg[3] * x0.w;
            a += wreg[4] * x1.x;  a += wreg[5] * x1.y;
            a += wreg[6] * x1.z;  a += wreg[7] * x1.w;
            a += wreg[8] * x2.x;  a += wreg[9] * x2.y;
            a += wreg[10] * x2.z; a += wreg[11] * x2.w;
            a += wreg[12] * x3.x; a += wreg[13] * x3.y;
            a += wreg[14] * x3.z; a += wreg[15] * x3.w;
            acc[r] = a;
        }
    }

    float bv = 0.f;
    if (EPI == 1) bv = bias[lane];
#pragma unroll
    for (int r = 0; r < 16; ++r) {
        const int row = row0 + rbase + r;
        if (row < n) {
            float v = acc[r];
            if (EPI == 1) v = fmaxf(v + bv, 0.f);
            Y[(size_t)row * HD + lane] = v;
        }
    }
}

// ---------------------------------------------------------------------------
// Edge scatter: agg[dst[e]][:] += Y[src[e]][:]   (16 threads/edge, float4 each)
// ---------------------------------------------------------------------------
__global__ __launch_bounds__(256) void edge_scatter(const float* __restrict__ Y,
                                                    const int* __restrict__ src,
                                                    const int* __restrict__ dst,
                                                    float* __restrict__ agg, int E) {
    const int t = blockIdx.x * 256 + threadIdx.x;
    const int e = t >> 4;
    if (e >= E) return;
    const int q = (t & 15) << 2;
    const int s = src[e];
    const int d = dst[e];
    const float4 v = *(const float4*)&Y[(size_t)s * HD + q];
    float* a = &agg[(size_t)d * HD + q];
    unsafeAtomicAdd(a + 0, v.x);
    unsafeAtomicAdd(a + 1, v.y);
    unsafeAtomicAdd(a + 2, v.z);
    unsafeAtomicAdd(a + 3, v.w);
}

// ---------------------------------------------------------------------------
// Y = relu(Y + A + bias[col])   elementwise over n x 64, float4
// ---------------------------------------------------------------------------
__global__ __launch_bounds__(256) void add_bias_relu(float* __restrict__ Y,
                                                     const float* __restrict__ A,
                                                     const float* __restrict__ bias,
                                                     int n) {
    const int i = blockIdx.x * 256 + threadIdx.x;  // float4 index
    const int total = n * (HD / 4);
    if (i >= total) return;
    const float4 y = ((const float4*)Y)[i];
    const float4 a = ((const float4*)A)[i];
    const int c = (i & (HD / 4 - 1)) * 4;
    const float4 b = *(const float4*)&bias[c];
    float4 r;
    r.x = fmaxf(y.x + a.x + b.x, 0.f);
    r.y = fmaxf(y.y + a.y + b.y, 0.f);
    r.z = fmaxf(y.z + a.z + b.z, 0.f);
    r.w = fmaxf(y.w + a.w + b.w, 0.f);
    ((float4*)Y)[i] = r;
}

// ---------------------------------------------------------------------------
// Per-graph pooling: sums[batch[n]][:] += H2[n][:], counts[batch[n]] += 1
// ---------------------------------------------------------------------------
__global__ __launch_bounds__(256) void pool_scatter(const float* __restrict__ H2,
                                                    const int* __restrict__ batch,
                                                    float* __restrict__ sums,
                                                    float* __restrict__ counts, int n) {
    const int t = blockIdx.x * 256 + threadIdx.x;
    const int node = t >> 4;
    if (node >= n) return;
    const int q = (t & 15) << 2;
    const int g = batch[node];
    const float4 v = *(const float4*)&H2[(size_t)node * HD + q];
    float* s = &sums[(size_t)g * HD + q];
    unsafeAtomicAdd(s + 0, v.x);
    unsafeAtomicAdd(s + 1, v.y);
    unsafeAtomicAdd(s + 2, v.z);
    unsafeAtomicAdd(s + 3, v.w);
    if ((t & 15) == 0) unsafeAtomicAdd(&counts[g], 1.0f);
}

// ---------------------------------------------------------------------------
// out[g][c] = (sums[g][:]/max(counts[g],1)) . Wf[:][c] + bf[c]
// ---------------------------------------------------------------------------
__global__ __launch_bounds__(256) void final_linear(const float* __restrict__ sums,
                                                    const float* __restrict__ counts,
                                                    const float* __restrict__ Wf,
                                                    const float* __restrict__ bfv,
                                                    float* __restrict__ out, int G, int C) {
    const int t = blockIdx.x * 256 + threadIdx.x;
    if (t >= G * C) return;
    const int g = t / C;
    const int c = t - g * C;
    const float inv = 1.0f / fmaxf(counts[g], 1.0f);
    float acc = 0.f;
    for (int h = 0; h < HD; ++h) acc += sums[(size_t)g * HD + h] * Wf[h * C + c];
    out[t] = acc * inv + bfv[c];
}

extern "C" void kernel_launch(void* const* d_in, const int* in_sizes, int n_in,
                              void* d_out, int out_size, void* d_ws, size_t ws_size,
                              hipStream_t stream) {
    const float* x    = (const float*)d_in[0];
    const int*   ei   = (const int*)d_in[1];
    const int*   batc = (const int*)d_in[2];
    const float* W1a  = (const float*)d_in[3];
    const float* b1a  = (const float*)d_in[4];
    const float* W1b  = (const float*)d_in[5];
    const float* b1b  = (const float*)d_in[6];
    const float* W2a  = (const float*)d_in[7];
    const float* b2a  = (const float*)d_in[8];
    const float* W2b  = (const float*)d_in[9];
    const float* b2b  = (const float*)d_in[10];
    const float* Wf   = (const float*)d_in[11];
    const float* bfv  = (const float*)d_in[12];

    const int n = in_sizes[2];       // 100000 nodes
    const int E = in_sizes[1] / 2;   // 1M edges
    const int C = in_sizes[12];      // 2 classes
    const int G = out_size / C;      // 1000 graphs

    const int* src = ei;
    const int* dst = ei + E;

    float* bufA   = (float*)d_ws;                 // n x 64
    float* bufB   = bufA + (size_t)n * HD;        // n x 64
    float* sums   = bufB + (size_t)n * HD;        // G x 64
    float* counts = sums + (size_t)G * HD;        // G   (contiguous after sums)

    const int gemmGrid = (n + 63) / 64;
    const int scatGrid = (E * 16 + 255) / 256;
    const int ewGrid   = (n * (HD / 4) + 255) / 256;
    const int poolGrid = (n * 16 + 255) / 256;

    // ---- Layer 1:  t1 = relu(x@W1a + agg(x@W1a) + b1a); h1 = relu(t1@W1b + b1b)
    gemm_k<128, 0><<<gemmGrid, 256, 0, stream>>>(x, W1a, nullptr, bufA, n);
    hipMemsetAsync(bufB, 0, (size_t)n * HD * sizeof(float), stream);
    edge_scatter<<<scatGrid, 256, 0, stream>>>(bufA, src, dst, bufB, E);
    add_bias_relu<<<ewGrid, 256, 0, stream>>>(bufA, bufB, b1a, n);
    gemm_k<64, 1><<<gemmGrid, 256, 0, stream>>>(bufA, W1b, b1b, bufB, n);  // h1 -> bufB

    // ---- Layer 2
    gemm_k<64, 0><<<gemmGrid, 256, 0, stream>>>(bufB, W2a, nullptr, bufA, n);  // y2 -> bufA
    hipMemsetAsync(bufB, 0, (size_t)n * HD * sizeof(float), stream);
    edge_scatter<<<scatGrid, 256, 0, stream>>>(bufA, src, dst, bufB, E);
    add_bias_relu<<<ewGrid, 256, 0, stream>>>(bufA, bufB, b2a, n);
    gemm_k<64, 1><<<gemmGrid, 256, 0, stream>>>(bufA, W2b, b2b, bufB, n);  // h2 -> bufB

    // ---- Pool + final linear
    hipMemsetAsync(sums, 0, (size_t)G * (HD + 1) * sizeof(float), stream);
    pool_scatter<<<poolGrid, 256, 0, stream>>>(bufB, batc, sums, counts, n);
    final_linear<<<(G * C + 255) / 256, 256, 0, stream>>>(sums, counts, Wf, bfv,
                                                          (float*)d_out, G, C);
}

// Round 2
// 2059.270 us; speedup vs baseline: 2.4677x; 2.4677x over previous
//
#include <hip/hip_runtime.h>

#define HD 64  // hidden dim (columns of every GEMM here)

// ---------------------------------------------------------------------------
// GEMM: Y[n x 64] = X[n x K] @ W[K x 64]
//   PRE==1: X = relu(Xa + Xb + bpre[col])  (computed during LDS staging)
//   EPI==1: Y = relu(acc + bepi[col])
// Block = 256 threads (4 waves), 64 rows per block. Wave w owns rows
// [w*16, w*16+16); each lane owns one output column. W cached 8 k's at a
// time in registers (reused across 16 rows); X reads are wave-uniform LDS
// broadcasts (conflict-free). k-loop NOT fully unrolled (round-1 spill fix).
// In-place Y==Xa is safe: block stages all its rows to LDS before writing.
// ---------------------------------------------------------------------------
template <int K, int PRE, int EPI>
__global__ __launch_bounds__(256) void gemm_k(const float* __restrict__ Xa,
                                              const float* __restrict__ Xb,
                                              const float* __restrict__ bpre,
                                              const float* __restrict__ W,
                                              const float* __restrict__ bepi,
                                              float* __restrict__ Y, int n) {
    __shared__ float Ws[K][HD];   // Ws[k][c]; lane->consecutive c = conflict-free
    __shared__ float Xs[64][K];   // 64-row X tile; reads are wave-uniform broadcasts

    const int tid  = threadIdx.x;
    const int lane = tid & 63;
    const int wid  = tid >> 6;    // 0..3
    const int row0 = blockIdx.x * 64;

    // stage W (coalesced b32)
    for (int i = tid; i < K * HD; i += 256) {
        Ws[i >> 6][i & 63] = W[i];
    }
    // stage X tile (float4, coalesced); PRE fuses relu(Xa + Xb + bpre)
    {
        const int rowf4 = K / 4;
        const float4* Xga = (const float4*)Xa;
        const float4* Xgb = (const float4*)Xb;
        float4* Xl = (float4*)&Xs[0][0];
        for (int i = tid; i < 64 * rowf4; i += 256) {
            const int r   = i / rowf4;
            const int c4  = i - r * rowf4;
            const int row = row0 + r;
            float4 v = make_float4(0.f, 0.f, 0.f, 0.f);
            if (row < n) {
                v = Xga[(size_t)row * rowf4 + c4];
                if (PRE) {
                    const float4 u = Xgb[(size_t)row * rowf4 + c4];
                    const float4 b = *(const float4*)&bpre[c4 * 4];
                    v.x = fmaxf(v.x + u.x + b.x, 0.f);
                    v.y = fmaxf(v.y + u.y + b.y, 0.f);
                    v.z = fmaxf(v.z + u.z + b.z, 0.f);
                    v.w = fmaxf(v.w + u.w + b.w, 0.f);
                }
            }
            Xl[i] = v;
        }
    }
    __syncthreads();

    float acc[16];
#pragma unroll
    for (int r = 0; r < 16; ++r) acc[r] = 0.f;

    const int rbase = wid * 16;
#pragma unroll 1                      // round-1 lesson: full unroll -> 256 VGPR + 3.7GB spill
    for (int k0 = 0; k0 < K; k0 += 8) {
        float wreg[8];
#pragma unroll
        for (int j = 0; j < 8; ++j) wreg[j] = Ws[k0 + j][lane];
#pragma unroll
        for (int r = 0; r < 16; ++r) {
            const float4 x0 = *(const float4*)&Xs[rbase + r][k0 + 0];
            const float4 x1 = *(const float4*)&Xs[rbase + r][k0 + 4];
            float a = acc[r];
            a = fmaf(wreg[0], x0.x, a);
            a = fmaf(wreg[1], x0.y, a);
            a = fmaf(wreg[2], x0.z, a);
            a = fmaf(wreg[3], x0.w, a);
            a = fmaf(wreg[4], x1.x, a);
            a = fmaf(wreg[5], x1.y, a);
            a = fmaf(wreg[6], x1.z, a);
            a = fmaf(wreg[7], x1.w, a);
            acc[r] = a;
        }
    }

    const float bv = EPI ? bepi[lane] : 0.f;
#pragma unroll
    for (int r = 0; r < 16; ++r) {
        const int row = row0 + rbase + r;
        if (row < n) {
            float v = acc[r];
            if (EPI) v = fmaxf(v + bv, 0.f);
            Y[(size_t)row * HD + lane] = v;
        }
    }
}

// ---------------------------------------------------------------------------
// Edge scatter: agg[dst[e]][:] += Y[src[e]][:]   (16 threads/edge, float4 each)
// ---------------------------------------------------------------------------
__global__ __launch_bounds__(256) void edge_scatter(const float* __restrict__ Y,
                                                    const int* __restrict__ src,
                                                    const int* __restrict__ dst,
                                                    float* __restrict__ agg, int E) {
    const int t = blockIdx.x * 256 + threadIdx.x;
    const int e = t >> 4;
    if (e >= E) return;
    const int q = (t & 15) << 2;
    const int s = src[e];
    const int d = dst[e];
    const float4 v = *(const float4*)&Y[(size_t)s * HD + q];
    float* a = &agg[(size_t)d * HD + q];
    unsafeAtomicAdd(a + 0, v.x);
    unsafeAtomicAdd(a + 1, v.y);
    unsafeAtomicAdd(a + 2, v.z);
    unsafeAtomicAdd(a + 3, v.w);
}

// ---------------------------------------------------------------------------
// Per-graph pooling: sums[batch[n]][:] += H2[n][:], counts[batch[n]] += 1
// ---------------------------------------------------------------------------
__global__ __launch_bounds__(256) void pool_scatter(const float* __restrict__ H2,
                                                    const int* __restrict__ batch,
                                                    float* __restrict__ sums,
                                                    float* __restrict__ counts, int n) {
    const int t = blockIdx.x * 256 + threadIdx.x;
    const int node = t >> 4;
    if (node >= n) return;
    const int q = (t & 15) << 2;
    const int g = batch[node];
    const float4 v = *(const float4*)&H2[(size_t)node * HD + q];
    float* s = &sums[(size_t)g * HD + q];
    unsafeAtomicAdd(s + 0, v.x);
    unsafeAtomicAdd(s + 1, v.y);
    unsafeAtomicAdd(s + 2, v.z);
    unsafeAtomicAdd(s + 3, v.w);
    if ((t & 15) == 0) unsafeAtomicAdd(&counts[g], 1.0f);
}

// ---------------------------------------------------------------------------
// out[g][c] = (sums[g][:]/max(counts[g],1)) . Wf[:][c] + bf[c]
// ---------------------------------------------------------------------------
__global__ __launch_bounds__(256) void final_linear(const float* __restrict__ sums,
                                                    const float* __restrict__ counts,
                                                    const float* __restrict__ Wf,
                                                    const float* __restrict__ bfv,
                                                    float* __restrict__ out, int G, int C) {
    const int t = blockIdx.x * 256 + threadIdx.x;
    if (t >= G * C) return;
    const int g = t / C;
    const int c = t - g * C;
    const float inv = 1.0f / fmaxf(counts[g], 1.0f);
    float acc = 0.f;
    for (int h = 0; h < HD; ++h) acc += sums[(size_t)g * HD + h] * Wf[h * C + c];
    out[t] = acc * inv + bfv[c];
}

extern "C" void kernel_launch(void* const* d_in, const int* in_sizes, int n_in,
                              void* d_out, int out_size, void* d_ws, size_t ws_size,
                              hipStream_t stream) {
    const float* x    = (const float*)d_in[0];
    const int*   ei   = (const int*)d_in[1];
    const int*   batc = (const int*)d_in[2];
    const float* W1a  = (const float*)d_in[3];
    const float* b1a  = (const float*)d_in[4];
    const float* W1b  = (const float*)d_in[5];
    const float* b1b  = (const float*)d_in[6];
    const float* W2a  = (const float*)d_in[7];
    const float* b2a  = (const float*)d_in[8];
    const float* W2b  = (const float*)d_in[9];
    const float* b2b  = (const float*)d_in[10];
    const float* Wf   = (const float*)d_in[11];
    const float* bfv  = (const float*)d_in[12];

    const int n = in_sizes[2];       // 100000 nodes
    const int E = in_sizes[1] / 2;   // 1M edges
    const int C = in_sizes[12];      // 2 classes
    const int G = out_size / C;      // 1000 graphs

    const int* src = ei;
    const int* dst = ei + E;

    float* bufA   = (float*)d_ws;                 // n x 64
    float* bufB   = bufA + (size_t)n * HD;        // n x 64
    float* sums   = bufB + (size_t)n * HD;        // G x 64
    float* counts = sums + (size_t)G * HD;        // G

    const int gemmGrid = (n + 63) / 64;
    const int scatGrid = (E * 16 + 255) / 256;
    const int poolGrid = (n * 16 + 255) / 256;
    const size_t nodeBytes = (size_t)n * HD * sizeof(float);

    // ---- Layer 1: y1 = x@W1a; agg1 = scatter(y1); h1 = relu(relu(y1+agg1+b1a)@W1b+b1b)
    gemm_k<128, 0, 0><<<gemmGrid, 256, 0, stream>>>(x, nullptr, nullptr, W1a, nullptr, bufA, n);
    hipMemsetAsync(bufB, 0, nodeBytes, stream);
    edge_scatter<<<scatGrid, 256, 0, stream>>>(bufA, src, dst, bufB, E);
    gemm_k<64, 1, 1><<<gemmGrid, 256, 0, stream>>>(bufA, bufB, b1a, W1b, b1b, bufA, n);  // h1 -> bufA (in-place safe)

    // ---- Layer 2: y2 = h1@W2a; agg2 = scatter(y2); h2 = relu(relu(y2+agg2+b2a)@W2b+b2b)
    gemm_k<64, 0, 0><<<gemmGrid, 256, 0, stream>>>(bufA, nullptr, nullptr, W2a, nullptr, bufB, n);  // y2 -> bufB
    hipMemsetAsync(bufA, 0, nodeBytes, stream);
    edge_scatter<<<scatGrid, 256, 0, stream>>>(bufB, src, dst, bufA, E);
    gemm_k<64, 1, 1><<<gemmGrid, 256, 0, stream>>>(bufB, bufA, b2a, W2b, b2b, bufB, n);  // h2 -> bufB (in-place safe)

    // ---- Pool + final linear
    hipMemsetAsync(sums, 0, (size_t)G * (HD + 1) * sizeof(float), stream);
    pool_scatter<<<poolGrid, 256, 0, stream>>>(bufB, batc, sums, counts, n);
    final_linear<<<(G * C + 255) / 256, 256, 0, stream>>>(sums, counts, Wf, bfv,
                                                          (float*)d_out, G, C);
}

// Round 3
// 416.078 us; speedup vs baseline: 12.2131x; 4.9492x over previous
//
#include <hip/hip_runtime.h>

#define HD 64  // hidden dim (columns of every GEMM here)

// ---------------------------------------------------------------------------
// GEMM: Y[n x 64] = X[n x K] @ W[K x 64]
//   PRE==1: X = relu(Xa + Xb + bpre[col])  (computed during LDS staging)
//   EPI==1: Y = relu(acc + bepi[col])
// Block = 256 threads (4 waves), 64 rows per block. k-loop NOT fully
// unrolled (round-1 lesson: full unroll -> 256 VGPR + 3.7 GB spill traffic).
// In-place Y==Xa is safe: block stages all its rows to LDS before writing.
// ---------------------------------------------------------------------------
template <int K, int PRE, int EPI>
__global__ __launch_bounds__(256) void gemm_k(const float* __restrict__ Xa,
                                              const float* __restrict__ Xb,
                                              const float* __restrict__ bpre,
                                              const float* __restrict__ W,
                                              const float* __restrict__ bepi,
                                              float* __restrict__ Y, int n) {
    __shared__ float Ws[K][HD];   // Ws[k][c]; lane->consecutive c = conflict-free
    __shared__ float Xs[64][K];   // 64-row X tile; reads are wave-uniform broadcasts

    const int tid  = threadIdx.x;
    const int lane = tid & 63;
    const int wid  = tid >> 6;    // 0..3
    const int row0 = blockIdx.x * 64;

    for (int i = tid; i < K * HD; i += 256) {
        Ws[i >> 6][i & 63] = W[i];
    }
    {
        const int rowf4 = K / 4;
        const float4* Xga = (const float4*)Xa;
        const float4* Xgb = (const float4*)Xb;
        float4* Xl = (float4*)&Xs[0][0];
        for (int i = tid; i < 64 * rowf4; i += 256) {
            const int r   = i / rowf4;
            const int c4  = i - r * rowf4;
            const int row = row0 + r;
            float4 v = make_float4(0.f, 0.f, 0.f, 0.f);
            if (row < n) {
                v = Xga[(size_t)row * rowf4 + c4];
                if (PRE) {
                    const float4 u = Xgb[(size_t)row * rowf4 + c4];
                    const float4 b = *(const float4*)&bpre[c4 * 4];
                    v.x = fmaxf(v.x + u.x + b.x, 0.f);
                    v.y = fmaxf(v.y + u.y + b.y, 0.f);
                    v.z = fmaxf(v.z + u.z + b.z, 0.f);
                    v.w = fmaxf(v.w + u.w + b.w, 0.f);
                }
            }
            Xl[i] = v;
        }
    }
    __syncthreads();

    float acc[16];
#pragma unroll
    for (int r = 0; r < 16; ++r) acc[r] = 0.f;

    const int rbase = wid * 16;
#pragma unroll 1
    for (int k0 = 0; k0 < K; k0 += 8) {
        float wreg[8];
#pragma unroll
        for (int j = 0; j < 8; ++j) wreg[j] = Ws[k0 + j][lane];
#pragma unroll
        for (int r = 0; r < 16; ++r) {
            const float4 x0 = *(const float4*)&Xs[rbase + r][k0 + 0];
            const float4 x1 = *(const float4*)&Xs[rbase + r][k0 + 4];
            float a = acc[r];
            a = fmaf(wreg[0], x0.x, a);
            a = fmaf(wreg[1], x0.y, a);
            a = fmaf(wreg[2], x0.z, a);
            a = fmaf(wreg[3], x0.w, a);
            a = fmaf(wreg[4], x1.x, a);
            a = fmaf(wreg[5], x1.y, a);
            a = fmaf(wreg[6], x1.z, a);
            a = fmaf(wreg[7], x1.w, a);
            acc[r] = a;
        }
    }

    const float bv = EPI ? bepi[lane] : 0.f;
#pragma unroll
    for (int r = 0; r < 16; ++r) {
        const int row = row0 + rbase + r;
        if (row < n) {
            float v = acc[r];
            if (EPI) v = fmaxf(v + bv, 0.f);
            Y[(size_t)row * HD + lane] = v;
        }
    }
}

// ---------------------------------------------------------------------------
// CSR build (replaces atomic fp32 scatter; round-2 lesson: 64M fp32 atomics
// = 1 GB HBM write-through, 850 us/pass). Fill order is nondeterministic but
// each node's slot range is contiguous regardless of order.
// ---------------------------------------------------------------------------
__global__ __launch_bounds__(256) void count_deg(const int* __restrict__ dst,
                                                 int* __restrict__ deg, int E) {
    const int t = blockIdx.x * 256 + threadIdx.x;
    if (t < E) atomicAdd(&deg[dst[t]], 1);
}

// Wave-ticket exclusive scan: 4 nodes/thread, 1 global atomic per wave.
__global__ __launch_bounds__(256) void assign_starts(const int* __restrict__ deg,
                                                     int* __restrict__ start,
                                                     int* __restrict__ fillpos,
                                                     int* __restrict__ cursor, int n) {
    const int t     = blockIdx.x * 256 + threadIdx.x;
    const int lane  = threadIdx.x & 63;
    const int base4 = t * 4;
    int d[4];
    int tot = 0;
#pragma unroll
    for (int i = 0; i < 4; ++i) {
        d[i] = (base4 + i < n) ? deg[base4 + i] : 0;
        tot += d[i];
    }
    // wave inclusive scan of tot
    int pfx = tot;
#pragma unroll
    for (int off = 1; off < 64; off <<= 1) {
        const int y = __shfl_up(pfx, off);
        if (lane >= off) pfx += y;
    }
    const int excl = pfx - tot;
    int base = 0;
    if (lane == 63) base = atomicAdd(cursor, pfx);  // pfx@63 == wave total
    base = __shfl(base, 63);
    int s = base + excl;
#pragma unroll
    for (int i = 0; i < 4; ++i) {
        if (base4 + i < n) {
            start[base4 + i]   = s;
            fillpos[base4 + i] = s;
        }
        s += d[i];
    }
}

__global__ __launch_bounds__(256) void fill_csr(const int* __restrict__ src,
                                                const int* __restrict__ dst,
                                                int* __restrict__ fillpos,
                                                int* __restrict__ eidx, int E) {
    const int t = blockIdx.x * 256 + threadIdx.x;
    if (t < E) {
        const int p = atomicAdd(&fillpos[dst[t]], 1);
        eidx[p] = src[t];
    }
}

// ---------------------------------------------------------------------------
// Gather aggregation: agg[v][:] = sum over edges of Y[src][:]
// One wave per node, lane = column. endp == fillpos after fill (start+deg).
// No atomics, no prior memset (overwrites).
// ---------------------------------------------------------------------------
__global__ __launch_bounds__(256) void gather_agg(const float* __restrict__ Y,
                                                  const int* __restrict__ start,
                                                  const int* __restrict__ endp,
                                                  const int* __restrict__ eidx,
                                                  float* __restrict__ agg, int n) {
    const int wid  = threadIdx.x >> 6;
    const int lane = threadIdx.x & 63;
    const int v    = blockIdx.x * 4 + wid;
    if (v >= n) return;
    const int s = start[v];
    const int e = endp[v];
    float acc = 0.f;
    int j = s;
    for (; j + 1 < e; j += 2) {
        const int u0 = eidx[j];
        const int u1 = eidx[j + 1];
        acc += Y[(size_t)u0 * HD + lane];
        acc += Y[(size_t)u1 * HD + lane];
    }
    if (j < e) acc += Y[(size_t)eidx[j] * HD + lane];
    agg[(size_t)v * HD + lane] = acc;
}

// ---------------------------------------------------------------------------
// Segmented pooling: batch is sorted -> accumulate runs of equal g in
// registers, flush one 64-lane atomic row per run (not per node).
// Wave handles 16 consecutive nodes (avg run length ~100 -> ~1 flush/wave).
// ---------------------------------------------------------------------------
__global__ __launch_bounds__(256) void pool_seg(const float* __restrict__ H2,
                                                const int* __restrict__ batch,
                                                float* __restrict__ sums,
                                                float* __restrict__ counts, int n) {
    const int lane = threadIdx.x & 63;
    const int wid  = threadIdx.x >> 6;
    const int v0   = (blockIdx.x * 4 + wid) * 16;
    if (v0 >= n) return;
    const int vend = min(v0 + 16, n);
    int   curg = batch[v0];
    float acc  = 0.f;
    float cnt  = 0.f;
    for (int v = v0; v < vend; ++v) {
        const int g = batch[v];  // wave-uniform
        if (g != curg) {
            unsafeAtomicAdd(&sums[(size_t)curg * HD + lane], acc);
            if (lane == 0) unsafeAtomicAdd(&counts[curg], cnt);
            curg = g;
            acc  = 0.f;
            cnt  = 0.f;
        }
        acc += H2[(size_t)v * HD + lane];
        cnt += 1.f;
    }
    unsafeAtomicAdd(&sums[(size_t)curg * HD + lane], acc);
    if (lane == 0) unsafeAtomicAdd(&counts[curg], cnt);
}

// ---------------------------------------------------------------------------
// out[g][c] = (sums[g][:]/max(counts[g],1)) . Wf[:][c] + bf[c]
// ---------------------------------------------------------------------------
__global__ __launch_bounds__(256) void final_linear(const float* __restrict__ sums,
                                                    const float* __restrict__ counts,
                                                    const float* __restrict__ Wf,
                                                    const float* __restrict__ bfv,
                                                    float* __restrict__ out, int G, int C) {
    const int t = blockIdx.x * 256 + threadIdx.x;
    if (t >= G * C) return;
    const int g = t / C;
    const int c = t - g * C;
    const float inv = 1.0f / fmaxf(counts[g], 1.0f);
    float acc = 0.f;
    for (int h = 0; h < HD; ++h) acc += sums[(size_t)g * HD + h] * Wf[h * C + c];
    out[t] = acc * inv + bfv[c];
}

extern "C" void kernel_launch(void* const* d_in, const int* in_sizes, int n_in,
                              void* d_out, int out_size, void* d_ws, size_t ws_size,
                              hipStream_t stream) {
    const float* x    = (const float*)d_in[0];
    const int*   ei   = (const int*)d_in[1];
    const int*   batc = (const int*)d_in[2];
    const float* W1a  = (const float*)d_in[3];
    const float* b1a  = (const float*)d_in[4];
    const float* W1b  = (const float*)d_in[5];
    const float* b1b  = (const float*)d_in[6];
    const float* W2a  = (const float*)d_in[7];
    const float* b2a  = (const float*)d_in[8];
    const float* W2b  = (const float*)d_in[9];
    const float* b2b  = (const float*)d_in[10];
    const float* Wf   = (const float*)d_in[11];
    const float* bfv  = (const float*)d_in[12];

    const int n = in_sizes[2];       // 100000 nodes
    const int E = in_sizes[1] / 2;   // 1M edges
    const int C = in_sizes[12];      // 2 classes
    const int G = out_size / C;      // 1000 graphs

    const int* src = ei;
    const int* dst = ei + E;

    // workspace layout
    float* bufA   = (float*)d_ws;                  // n x 64
    float* bufB   = bufA + (size_t)n * HD;         // n x 64
    float* sums   = bufB + (size_t)n * HD;         // G x 64
    float* counts = sums + (size_t)G * HD;         // G
    int*   deg    = (int*)(counts + G);            // n
    int*   start  = deg + n;                       // n
    int*   fillp  = start + n;                     // n (fill cursor; == end after fill)
    int*   cursor = fillp + n;                     // 1
    int*   eidx   = cursor + 1;                    // E

    const int gemmGrid = (n + 63) / 64;
    const int eGrid    = (E + 255) / 256;
    const int aggGrid  = (n + 3) / 4;
    const int poolGrid = (n + 16 * 4 - 1) / (16 * 4);

    // ---- CSR build (once, reused by both layers)
    hipMemsetAsync(deg, 0, (size_t)n * sizeof(int), stream);
    hipMemsetAsync(cursor, 0, sizeof(int), stream);
    count_deg<<<eGrid, 256, 0, stream>>>(dst, deg, E);
    assign_starts<<<(n + 1023) / 1024, 256, 0, stream>>>(deg, start, fillp, cursor, n);
    fill_csr<<<eGrid, 256, 0, stream>>>(src, dst, fillp, eidx, E);

    // ---- Layer 1: y1 = x@W1a; agg1 = gather(y1); h1 = relu(relu(y1+agg1+b1a)@W1b+b1b)
    gemm_k<128, 0, 0><<<gemmGrid, 256, 0, stream>>>(x, nullptr, nullptr, W1a, nullptr, bufA, n);
    gather_agg<<<aggGrid, 256, 0, stream>>>(bufA, start, fillp, eidx, bufB, n);
    gemm_k<64, 1, 1><<<gemmGrid, 256, 0, stream>>>(bufA, bufB, b1a, W1b, b1b, bufA, n);  // h1 -> bufA

    // ---- Layer 2
    gemm_k<64, 0, 0><<<gemmGrid, 256, 0, stream>>>(bufA, nullptr, nullptr, W2a, nullptr, bufB, n);  // y2 -> bufB
    gather_agg<<<aggGrid, 256, 0, stream>>>(bufB, start, fillp, eidx, bufA, n);
    gemm_k<64, 1, 1><<<gemmGrid, 256, 0, stream>>>(bufB, bufA, b2a, W2b, b2b, bufB, n);  // h2 -> bufB

    // ---- Pool + final linear
    hipMemsetAsync(sums, 0, (size_t)G * (HD + 1) * sizeof(float), stream);
    pool_seg<<<poolGrid, 256, 0, stream>>>(bufB, batc, sums, counts, n);
    final_linear<<<(G * C + 255) / 256, 256, 0, stream>>>(sums, counts, Wf, bfv,
                                                          (float*)d_out, G, C);
}